// Round 5
// baseline (1993.726 us; speedup 1.0000x reference)
//
#include <hip/hip_runtime.h>
#include <hip/hip_bf16.h>
#include <cstdint>
#include <cstddef>

// ---------------- problem constants ----------------
#define B_TOT   8192
#define T_TOT   128
#define ROWS    32          // batch rows per block
#define THREADS 1024        // 16 waves

typedef __bf16 bf16x8 __attribute__((ext_vector_type(8)));
typedef float  f32x4  __attribute__((ext_vector_type(4)));

// ---------------- ws layout (bytes) ----------------
#define WSF_X0    0      // 64 f32 : x0 row (uniform across batch)
#define WSF_BCD   64     // 128 f32: drift  layer0 cond-bias
#define WSF_BCG   192    // 128 f32: diff   layer0 cond-bias
#define WSF_ROB   320    // 8 f32  : readout bias (ro_b + c0 @ ro_W[64:68])
#define WSB_SMALL 1536                    // 49152 bf16 : packed Wd0x|Wd1|Wg0x|Wg1
#define WSB_WD2   (WSB_SMALL + 49152*2)   // 8192 bf16  : packed Wd2 (x0.909)
#define WSB_WG2   (WSB_WD2 + 8192*2)      // 131072 bf16: packed Wg2 (x0.909)
#define WSB_ROWP  (WSB_WG2 + 131072*2)    // 1024 bf16  : packed roW [64][16-pad]
#define WSB_TOTAL (WSB_ROWP + 1024*2)

__device__ __forceinline__ unsigned short f2bf(float v){
  union { float f; unsigned u; } x; x.f = v;
  unsigned r = (x.u + 0x7FFFu + ((x.u >> 16) & 1u)) >> 16;
  return (unsigned short)r;
}
__device__ __forceinline__ unsigned cvtpk(float lo, float hi){
  unsigned r;
  asm("v_cvt_pk_bf16_f32 %0, %1, %2" : "=v"(r) : "v"(lo), "v"(hi));
  return r;
}
__device__ __forceinline__ float fexp2(float x){ return __builtin_amdgcn_exp2f(x); }
__device__ __forceinline__ float frcp (float x){ return __builtin_amdgcn_rcpf(x); }
// x*sigmoid(x); the 0.909 lipswish factor is folded into the NEXT layer's W.
__device__ __forceinline__ float swishf(float x){
  float e = fexp2(-1.44269504088896340f * x);
  return x * frcp(1.0f + e);
}
__device__ __forceinline__ float tanhfast(float x){
  float e = fexp2(2.88539008177792681f * x);           // e^(2x)
  return 1.0f - 2.0f * frcp(e + 1.0f);
}
__device__ __forceinline__ f32x4 mfma16(bf16x8 a, bf16x8 b, f32x4 c){
  return __builtin_amdgcn_mfma_f32_16x16x32_bf16(a, b, c, 0, 0, 0);
}
// B^T-fragment read from a row-major [32 or 16][K] bf16 LDS tile with XOR swizzle.
__device__ __forceinline__ bf16x8 lds_bfrag(const unsigned short* buf, int rowBytes,
                                            int brow, int kByte){
  int off = brow * rowBytes + kByte;
  off ^= (brow & 7) << 4;
  return *(const bf16x8*)((const char*)buf + off);
}

// ============================================================
// prep kernel: fold c0/t into biases, pack weights to fragment
// layout: packed[(ot*KC+kc)*64 + lane]*8 + j = W[kc*32+(lane>>4)*8+j][ot*16+(lane&15)]
// W1 and W2 matrices are pre-scaled by 0.909 (lipswish constant).
// ============================================================
__global__ void prep_kernel(const float* __restrict__ cond,
    const float* __restrict__ drW0, const float* __restrict__ drb0,
    const float* __restrict__ drW1, const float* __restrict__ drW2,
    const float* __restrict__ diW0, const float* __restrict__ dib0,
    const float* __restrict__ diW1, const float* __restrict__ diW2,
    const float* __restrict__ initW, const float* __restrict__ initb,
    const float* __restrict__ roW,  const float* __restrict__ rob,
    char* __restrict__ ws)
{
  float* wsf = (float*)ws;
  unsigned short* wsm = (unsigned short*)(ws + WSB_SMALL);
  unsigned short* wd2 = (unsigned short*)(ws + WSB_WD2);
  unsigned short* wg2 = (unsigned short*)(ws + WSB_WG2);
  unsigned short* rwp = (unsigned short*)(ws + WSB_ROWP);
  int tid = blockIdx.x * blockDim.x + threadIdx.x;
  int nth = gridDim.x * blockDim.x;

  for (int h = tid; h < 64; h += nth){
    float s = initb[h];
    #pragma unroll
    for (int i = 0; i < 16; i++) s += initW[i*64 + h];
    #pragma unroll
    for (int c = 0; c < 4; c++) s += cond[c] * initW[(16+c)*64 + h];
    wsf[WSF_X0 + h] = s;
  }
  for (int j = tid; j < 128; j += nth){
    float sd = drb0[j], sg = dib0[j];
    #pragma unroll
    for (int c = 0; c < 4; c++){
      sd += cond[c] * drW0[(65+c)*128 + j];
      sg += cond[c] * diW0[(65+c)*128 + j];
    }
    wsf[WSF_BCD + j] = sd; wsf[WSF_BCG + j] = sg;
  }
  for (int d = tid; d < 8; d += nth){
    float s = rob[d];
    #pragma unroll
    for (int c = 0; c < 4; c++) s += cond[c] * roW[(64+c)*8 + d];
    wsf[WSF_ROB + d] = s;
  }
  for (int u = tid; u < 49152; u += nth){
    int j = u & 7, lane = (u >> 3) & 63, frag = u >> 9;
    int k8 = ((lane >> 4) << 3) + j, o16 = lane & 15;
    float v;
    if (frag < 16)      { int kc = frag & 1,      ot = frag >> 1;      v = drW0[(1 + kc*32 + k8)*128 + ot*16 + o16]; }
    else if (frag < 48) { int f = frag - 16; int kc = f & 3, ot = f >> 2; v = 0.909f * drW1[(kc*32 + k8)*128 + ot*16 + o16]; }
    else if (frag < 64) { int f = frag - 48; int kc = f & 1, ot = f >> 1; v = diW0[(1 + kc*32 + k8)*128 + ot*16 + o16]; }
    else                { int f = frag - 64; int kc = f & 3, ot = f >> 2; v = 0.909f * diW1[(kc*32 + k8)*128 + ot*16 + o16]; }
    wsm[u] = f2bf(v);
  }
  for (int u = tid; u < 8192; u += nth){   // Wd2 [128x64], KC=4, ot 0..3
    int j = u & 7, lane = (u >> 3) & 63, frag = u >> 9, kc = frag & 3, ot = frag >> 2;
    wd2[u] = f2bf(0.909f * drW2[(kc*32 + ((lane>>4)<<3) + j)*64 + ot*16 + (lane & 15)]);
  }
  for (int u = tid; u < 131072; u += nth){ // Wg2 [128x1024], KC=4, ot 0..63
    int j = u & 7, lane = (u >> 3) & 63, frag = u >> 9, kc = frag & 3, ot = frag >> 2;
    wg2[u] = f2bf(0.909f * diW2[(kc*32 + ((lane>>4)<<3) + j)*1024 + ot*16 + (lane & 15)]);
  }
  for (int u = tid; u < 1024; u += nth){   // roW [64][16-pad], KC=2, 1 ot
    int j = u & 7, lane = (u >> 3) & 63, kc = u >> 9;
    int k = kc*32 + ((lane>>4)<<3) + j, o = lane & 15;
    rwp[u] = (o < 8) ? f2bf(roW[k*8 + o]) : (unsigned short)0;
  }
}

// ============================================================
// main persistent kernel: 256 blocks x 1024 threads (16 waves),
// 32 batch rows per block, whole time loop on-chip.
// amdgpu_waves_per_eu(4,4): pins the allocator's occupancy TARGET to
// 4 waves/SIMD (all the 156KB LDS allows anyway) -> 512/4 = 128-VGPR
// budget. launch_bounds' 2nd arg is only a floor and was ignored
// (rounds 3/4 compiled to 64 VGPR + 2.3 GB/dispatch scratch spill).
// ============================================================
__global__ __launch_bounds__(THREADS)
__attribute__((amdgpu_waves_per_eu(4, 4)))
void sde_kernel(
    const float* __restrict__ dW,  const float* __restrict__ tsg,
    const float* __restrict__ drW0, const float* __restrict__ diW0, // row0 = t weights
    const float* __restrict__ bd1, const float* __restrict__ bg1,
    const float* __restrict__ bd2, const float* __restrict__ bg2,
    const char* __restrict__ ws, float* __restrict__ out)
{
  __shared__ unsigned short smallW[49152];  // 96 KB packed weights
  __shared__ unsigned short z1buf[2048];    // [32][64] bf16, swizzled
  __shared__ unsigned short ybuf[2048];     // [32][64] bf16, swizzled (y for readout)
  __shared__ unsigned short h1d[4096];      // [32][128] bf16 swz | doubles as bT f32[64][32]
  __shared__ unsigned short h1g[4096];      // [32][128] bf16 swz | doubles as aT f32[64][32]
  __shared__ unsigned short h2d[4096];
  __shared__ unsigned short h2g[4096];
  __shared__ float f1T[2048];               // [64][32] f32, idx = h*32 + (brow^(h&31))
  __shared__ float tsbuf[128];
  __shared__ float bcdS[128], bcgS[128];    // layer0 cond biases
  __shared__ float wtdS[128], wtgS[128];    // layer0 t-row weights
  __shared__ float bd1S[128], bg1S[128];    // layer1 biases
  __shared__ float bg2S[1024];              // diff layer2 bias
  __shared__ float dwcS[512], dwnS[512];    // dW[k][B0..B0+31][16], dW[k+1][...]
  __shared__ float robiasS[8];

  const float* wsf = (const float*)ws;
  const unsigned short* wsSmall = (const unsigned short*)(ws + WSB_SMALL);
  const unsigned short* wsWd2   = (const unsigned short*)(ws + WSB_WD2);
  const unsigned short* wsWg2   = (const unsigned short*)(ws + WSB_WG2);
  const unsigned short* wsRoWp  = (const unsigned short*)(ws + WSB_ROWP);

  const int tid = threadIdx.x;
  const int w  = tid >> 6;        // wave 0..15
  const int l  = tid & 63;        // lane
  const int lg = l >> 4;          // 0..3
  const int li = l & 15;          // 0..15
  const int B0 = blockIdx.x * ROWS;
  const int row = tid >> 5;           // 0..31  (elementwise mapping)
  const int h0  = (tid & 31) << 1;    // 0..62  (2 h-slots per thread)

  // ---- init staging ----
  {
    const uint4* src = (const uint4*)wsSmall;
    uint4* dst = (uint4*)smallW;
    for (int i = tid; i < 6144; i += THREADS) dst[i] = src[i];
    for (int i = tid; i < 128; i += THREADS){
      tsbuf[i] = tsg[i];
      bcdS[i] = wsf[WSF_BCD + i]; bcgS[i] = wsf[WSF_BCG + i];
      wtdS[i] = drW0[i];          wtgS[i] = diW0[i];
      bd1S[i] = bd1[i];           bg1S[i] = bg1[i];
    }
    for (int i = tid; i < 1024; i += THREADS) bg2S[i] = bg2[i];
    if (tid < 8) robiasS[tid] = wsf[WSF_ROB + tid];
  }

  // ---- per-thread state (2 h-slots each) ----
  float y[2], z[2], fz[2], az[2];
  #pragma unroll
  for (int j = 0; j < 2; j++){ float v = wsf[WSF_X0 + h0 + j]; y[j] = v; z[j] = v; }

  auto writeZ = [&](){
    unsigned v = cvtpk(z[0], z[1]);
    int off = row*128 + (h0 << 1); off ^= (row & 7) << 4;
    *(unsigned*)((char*)z1buf + off) = v;
  };
  auto writeY = [&](){
    unsigned v = cvtpk(y[0], y[1]);
    int off = row*128 + (h0 << 1); off ^= (row & 7) << 4;
    *(unsigned*)((char*)ybuf + off) = v;
  };
  writeZ(); writeY();   // z1buf <- x0, ybuf <- x0

  __syncthreads();

  // readout projection: waves 14/15, tile bm = w-14; done in P1 phase
  auto OUTPROJ = [&](int tcur){
    const int bm = w - 14, brow = bm*16 + li;
    bf16x8 rw0 = *(const bf16x8*)(wsRoWp + ((     l) << 3));
    bf16x8 rw1 = *(const bf16x8*)(wsRoWp + ((64 + l) << 3));
    bf16x8 yb0 = lds_bfrag(ybuf, 128, brow,      lg*16);
    bf16x8 yb1 = lds_bfrag(ybuf, 128, brow, 64 + lg*16);
    f32x4 acc = {0.f,0.f,0.f,0.f};
    acc = mfma16(rw0, yb0, acc);
    acc = mfma16(rw1, yb1, acc);
    float* orow = out + (size_t)(B0 + brow)*1152 + (size_t)tcur*9;
    if (lg < 2){
      #pragma unroll
      for (int r = 0; r < 4; r++) orow[1 + lg*4 + r] = acc[r] + robiasS[lg*4 + r];
    } else if (lg == 2){
      orow[0] = tsbuf[tcur];
    }
  };

  // ---- one full MLP pipeline evaluation at (tval, z1buf) ----
  auto PIPE = [&](float tval, int kdwc, int kdwn, int tcur){
    // stage dW slices into LDS (2 KB each, contiguous)
    if (tid < 256){
      const float* src = dW + ((tid < 128) ? (size_t)kdwc : (size_t)kdwn)*131072
                            + (size_t)B0*16;
      float* dst = (tid < 128) ? dwcS : dwnS;
      int i = tid & 127;
      *(f32x4*)(dst + i*4) = *(const f32x4*)(src + i*4);
    }
    // ---- P1: layer0 drift+diff : [128 out]x[32], K=64; wave = (p, ot) ----
    {
      const int p = w >> 3, ot = w & 7;
      bf16x8 zb[2][2];
      #pragma unroll
      for (int bm = 0; bm < 2; bm++)
        #pragma unroll
        for (int kc = 0; kc < 2; kc++)
          zb[bm][kc] = lds_bfrag(z1buf, 128, bm*16 + li, kc*64 + lg*16);
      const int base = p ? 24576 : 0;
      f32x4 bcv = *(const f32x4*)((p ? bcgS : bcdS) + ot*16 + lg*4);
      f32x4 wtv = *(const f32x4*)((p ? wtgS : wtdS) + ot*16 + lg*4);
      bf16x8 af0 = *(const bf16x8*)(smallW + base + ((ot*2 + 0)*64 + l)*8);
      bf16x8 af1 = *(const bf16x8*)(smallW + base + ((ot*2 + 1)*64 + l)*8);
      unsigned short* hout = p ? h1g : h1d;
      #pragma unroll
      for (int bm = 0; bm < 2; bm++){
        f32x4 acc = {0.f,0.f,0.f,0.f};
        acc = mfma16(af0, zb[bm][0], acc);
        acc = mfma16(af1, zb[bm][1], acc);
        int brow = bm*16 + li;
        float xx[4];
        #pragma unroll
        for (int r = 0; r < 4; r++) xx[r] = swishf(acc[r] + bcv[r] + tval*wtv[r]);
        int off = brow*256 + ((ot*16 + lg*4) << 1); off ^= (brow & 7) << 4;
        uint2 v; v.x = cvtpk(xx[0], xx[1]); v.y = cvtpk(xx[2], xx[3]);
        *(uint2*)((char*)hout + off) = v;
      }
      if (tcur >= 0 && w >= 14) OUTPROJ(tcur);
    }
    __syncthreads();
    // ---- P2: layer1 : wave = (p, ot), K=128 ----
    {
      const int p = w >> 3, ot = w & 7;
      const unsigned short* hin  = p ? h1g : h1d;
      unsigned short*       hout = p ? h2g : h2d;
      const float* b1 = p ? bg1S : bd1S;
      const int base = p ? 32768 : 8192;
      bf16x8 hb[2][4];
      #pragma unroll
      for (int bm = 0; bm < 2; bm++)
        #pragma unroll
        for (int kc = 0; kc < 4; kc++)
          hb[bm][kc] = lds_bfrag(hin, 256, bm*16 + li, kc*64 + lg*16);
      bf16x8 af[4];
      #pragma unroll
      for (int kc = 0; kc < 4; kc++)
        af[kc] = *(const bf16x8*)(smallW + base + ((ot*4 + kc)*64 + l)*8);
      f32x4 b1v = *(const f32x4*)(b1 + ot*16 + lg*4);
      #pragma unroll
      for (int bm = 0; bm < 2; bm++){
        f32x4 acc = {0.f,0.f,0.f,0.f};
        #pragma unroll
        for (int kc = 0; kc < 4; kc++) acc = mfma16(af[kc], hb[bm][kc], acc);
        int brow = bm*16 + li;
        float xx[4];
        #pragma unroll
        for (int r = 0; r < 4; r++) xx[r] = swishf(acc[r] + b1v[r]);
        int off = brow*256 + ((ot*16 + lg*4) << 1); off ^= (brow & 7) << 4;
        uint2 v; v.x = cvtpk(xx[0], xx[1]); v.y = cvtpk(xx[2], xx[3]);
        *(uint2*)((char*)hout + off) = v;
      }
    }
    __syncthreads();
    // ---- P3: drift L2 (waves 0-7) + diff L2 (all waves, 4 h each) ----
    {
      float* bT = (float*)h1d;
      float* aT = (float*)h1g;
      if (w < 8){ // drift: subtile (ot=w>>1, bm=w&1); weights streamed from L2
        const int ot = w >> 1, bm = w & 1, brow = bm*16 + li;
        bf16x8 wf[4], db[4];
        #pragma unroll
        for (int kc = 0; kc < 4; kc++){
          wf[kc] = *(const bf16x8*)(wsWd2 + ((ot*4 + kc)*64 + l)*8);
          db[kc] = lds_bfrag(h2d, 256, brow, kc*64 + lg*16);
        }
        f32x4 bdv = *(const f32x4*)(bd2 + ot*16 + lg*4);
        f32x4 acc = {0.f,0.f,0.f,0.f};
        #pragma unroll
        for (int kc = 0; kc < 4; kc++) acc = mfma16(wf[kc], db[kc], acc);
        #pragma unroll
        for (int r = 0; r < 4; r++){
          int h = ot*16 + lg*4 + r;
          f1T[h*32 + (brow ^ (h & 31))] = tanhfast(acc[r] + bdv[r]);
        }
      }
      // diffusion: wave handles h = w*4 .. w*4+3, Wg2 streamed from L2, dbuf'd
      bf16x8 gb[2][4];
      #pragma unroll
      for (int bm = 0; bm < 2; bm++)
        #pragma unroll
        for (int kc = 0; kc < 4; kc++)
          gb[bm][kc] = lds_bfrag(h2g, 256, bm*16 + li, kc*64 + lg*16);
      auto ldwg = [&](int ot, int kc) -> bf16x8 {
        return *(const bf16x8*)(wsWg2 + ((((w*4 + ot)*4 + kc)*64 + l) << 3));
      };
      auto G2 = [&](int ot, const bf16x8* f){
        const int h = w*4 + ot;
        f32x4 bgv = *(const f32x4*)(bg2S + h*16 + lg*4);
        #pragma unroll
        for (int bm = 0; bm < 2; bm++){
          const int brow = bm*16 + li;
          f32x4 acc = {0.f,0.f,0.f,0.f};
          #pragma unroll
          for (int kc = 0; kc < 4; kc++) acc = mfma16(f[kc], gb[bm][kc], acc);
          f32x4 dwcv = *(const f32x4*)(dwcS + brow*16 + lg*4);
          f32x4 dwnv = *(const f32x4*)(dwnS + brow*16 + lg*4);
          float bs = 0.f, as_ = 0.f;
          #pragma unroll
          for (int r = 0; r < 4; r++){
            float g = tanhfast(acc[r] + bgv[r]);
            bs  += g * dwcv[r];
            as_ += g * dwnv[r];
          }
          bs  += __shfl_xor(bs, 16);  bs  += __shfl_xor(bs, 32);
          as_ += __shfl_xor(as_, 16); as_ += __shfl_xor(as_, 32);
          const int idx = h*32 + (brow ^ (h & 31));
          if (lg == 0)      bT[idx] = bs;
          else if (lg == 1) aT[idx] = as_;
        }
      };
      bf16x8 fA[4], fB[4];
      #pragma unroll
      for (int kc = 0; kc < 4; kc++) fA[kc] = ldwg(0, kc);
      #pragma unroll 1
      for (int op = 0; op < 2; op++){
        const int o0 = op*2;
        #pragma unroll
        for (int kc = 0; kc < 4; kc++) fB[kc] = ldwg(o0 + 1, kc);
        G2(o0, fA);
        if (op < 1){
          #pragma unroll
          for (int kc = 0; kc < 4; kc++) fA[kc] = ldwg(o0 + 2, kc);
        }
        G2(o0 + 1, fB);
      }
    }
  };

  // ---- prologue: f0, g0 at (t0, x0); out(0) deferred to loop iter 0 ----
  PIPE(tsbuf[0], 0, 0, -1);
  __syncthreads();
  {
    #pragma unroll
    for (int j = 0; j < 2; j++){
      int h = h0 + j; int idx = h*32 + (row ^ (h & 31));
      fz[j] = f1T[idx];
      az[j] = ((const float*)h1g)[idx];      // a0 = g0 @ dW[0]
    }
    float dt0 = tsbuf[1] - tsbuf[0];
    #pragma unroll
    for (int j = 0; j < 2; j++) z[j] = 2.f*y[j] - z[j] + fz[j]*dt0 + az[j];
    writeZ();
  }
  __syncthreads();

  // ---- main time loop: iter k computes step k+1 and projects out(t=k) ----
  for (int k = 0; k < 127; k++){
    PIPE(tsbuf[k+1], k, (k < 126) ? (k+1) : 126, k);
    __syncthreads();
    float f1[2], bb[2], an[2];
    #pragma unroll
    for (int j = 0; j < 2; j++){
      int h = h0 + j; int idx = h*32 + (row ^ (h & 31));
      f1[j] = f1T[idx];
      bb[j] = ((const float*)h1d)[idx];
      an[j] = ((const float*)h1g)[idx];
    }
    float dtk = tsbuf[k+1] - tsbuf[k];
    #pragma unroll
    for (int j = 0; j < 2; j++){
      y[j] += 0.5f*dtk*(fz[j] + f1[j]) + 0.5f*(az[j] + bb[j]);
      fz[j] = f1[j]; az[j] = an[j];
    }
    writeY();
    if (k < 126){
      float dtn = tsbuf[k+2] - tsbuf[k+1];
      #pragma unroll
      for (int j = 0; j < 2; j++) z[j] = 2.f*y[j] - z[j] + fz[j]*dtn + az[j];
      writeZ();
    }
    __syncthreads();
  }

  // ---- epilogue: project out(t=127) from final ybuf ----
  if (w >= 14) OUTPROJ(127);
}

// ============================================================
extern "C" void kernel_launch(void* const* d_in, const int* in_sizes, int n_in,
                              void* d_out, int out_size, void* d_ws, size_t ws_size,
                              hipStream_t stream)
{
  const float* ts   = (const float*)d_in[0];
  const float* cond = (const float*)d_in[1];
  const float* dW   = (const float*)d_in[2];
  const float* drW0 = (const float*)d_in[3];
  const float* drb0 = (const float*)d_in[4];
  const float* drW1 = (const float*)d_in[5];
  const float* drb1 = (const float*)d_in[6];
  const float* drW2 = (const float*)d_in[7];
  const float* drb2 = (const float*)d_in[8];
  const float* diW0 = (const float*)d_in[9];
  const float* dib0 = (const float*)d_in[10];
  const float* diW1 = (const float*)d_in[11];
  const float* dib1 = (const float*)d_in[12];
  const float* diW2 = (const float*)d_in[13];
  const float* dib2 = (const float*)d_in[14];
  const float* initW= (const float*)d_in[15];
  const float* initb= (const float*)d_in[16];
  const float* roW  = (const float*)d_in[17];
  const float* rob  = (const float*)d_in[18];
  char* ws = (char*)d_ws;
  if (ws_size < (size_t)WSB_TOTAL) return;

  prep_kernel<<<dim3(256), dim3(256), 0, stream>>>(
      cond, drW0, drb0, drW1, drW2, diW0, dib0, diW1, diW2,
      initW, initb, roW, rob, ws);
  sde_kernel<<<dim3(256), dim3(THREADS), 0, stream>>>(
      dW, ts, drW0, diW0, drb1, dib1, drb2, dib2, ws, (float*)d_out);
}

// Round 6
// 1007.725 us; speedup vs baseline: 1.9784x; 1.9784x over previous
//
#include <hip/hip_runtime.h>
#include <hip/hip_bf16.h>
#include <cstdint>
#include <cstddef>

// ---------------- problem constants ----------------
#define B_TOT   8192
#define T_TOT   128
#define ROWS    32          // batch rows per block
#define THREADS 1024        // 16 waves

typedef __bf16 bf16x8 __attribute__((ext_vector_type(8)));
typedef float  f32x4  __attribute__((ext_vector_type(4)));

// ---------------- ws layout (bytes) ----------------
#define WSF_X0    0      // 64 f32 : x0 row (uniform across batch)
#define WSF_BCD   64     // 128 f32: drift  layer0 cond-bias
#define WSF_BCG   192    // 128 f32: diff   layer0 cond-bias
#define WSF_ROB   320    // 8 f32  : readout bias (ro_b + c0 @ ro_W[64:68])
#define WSB_SMALL 1536                    // 49152 bf16 : packed Wd0x|Wd1|Wg0x|Wg1
#define WSB_WD2   (WSB_SMALL + 49152*2)   // 8192 bf16  : packed Wd2 (x0.909)
#define WSB_WG2   (WSB_WD2 + 8192*2)      // 131072 bf16: packed Wg2 (x0.909)
#define WSB_ROWP  (WSB_WG2 + 131072*2)    // 1024 bf16  : packed roW [64][16-pad]
#define WSB_TOTAL (WSB_ROWP + 1024*2)

__device__ __forceinline__ unsigned short f2bf(float v){
  union { float f; unsigned u; } x; x.f = v;
  unsigned r = (x.u + 0x7FFFu + ((x.u >> 16) & 1u)) >> 16;
  return (unsigned short)r;
}
__device__ __forceinline__ unsigned cvtpk(float lo, float hi){
  unsigned r;
  asm("v_cvt_pk_bf16_f32 %0, %1, %2" : "=v"(r) : "v"(lo), "v"(hi));
  return r;
}
__device__ __forceinline__ float fexp2(float x){ return __builtin_amdgcn_exp2f(x); }
__device__ __forceinline__ float frcp (float x){ return __builtin_amdgcn_rcpf(x); }
// x*sigmoid(x); the 0.909 lipswish factor is folded into the NEXT layer's W.
__device__ __forceinline__ float swishf(float x){
  float e = fexp2(-1.44269504088896340f * x);
  return x * frcp(1.0f + e);
}
__device__ __forceinline__ float tanhfast(float x){
  float e = fexp2(2.88539008177792681f * x);           // e^(2x)
  return 1.0f - 2.0f * frcp(e + 1.0f);
}
__device__ __forceinline__ f32x4 mfma16(bf16x8 a, bf16x8 b, f32x4 c){
  return __builtin_amdgcn_mfma_f32_16x16x32_bf16(a, b, c, 0, 0, 0);
}
// B^T-fragment read from a row-major [32 or 16][K] bf16 LDS tile with XOR swizzle.
__device__ __forceinline__ bf16x8 lds_bfrag(const unsigned short* buf, int rowBytes,
                                            int brow, int kByte){
  int off = brow * rowBytes + kByte;
  off ^= (brow & 7) << 4;
  return *(const bf16x8*)((const char*)buf + off);
}

// ============================================================
// prep kernel: fold c0/t into biases, pack weights to fragment
// layout: packed[(ot*KC+kc)*64 + lane]*8 + j = W[kc*32+(lane>>4)*8+j][ot*16+(lane&15)]
// W1 and W2 matrices are pre-scaled by 0.909 (lipswish constant).
// ============================================================
__global__ void prep_kernel(const float* __restrict__ cond,
    const float* __restrict__ drW0, const float* __restrict__ drb0,
    const float* __restrict__ drW1, const float* __restrict__ drW2,
    const float* __restrict__ diW0, const float* __restrict__ dib0,
    const float* __restrict__ diW1, const float* __restrict__ diW2,
    const float* __restrict__ initW, const float* __restrict__ initb,
    const float* __restrict__ roW,  const float* __restrict__ rob,
    char* __restrict__ ws)
{
  float* wsf = (float*)ws;
  unsigned short* wsm = (unsigned short*)(ws + WSB_SMALL);
  unsigned short* wd2 = (unsigned short*)(ws + WSB_WD2);
  unsigned short* wg2 = (unsigned short*)(ws + WSB_WG2);
  unsigned short* rwp = (unsigned short*)(ws + WSB_ROWP);
  int tid = blockIdx.x * blockDim.x + threadIdx.x;
  int nth = gridDim.x * blockDim.x;

  for (int h = tid; h < 64; h += nth){
    float s = initb[h];
    #pragma unroll
    for (int i = 0; i < 16; i++) s += initW[i*64 + h];
    #pragma unroll
    for (int c = 0; c < 4; c++) s += cond[c] * initW[(16+c)*64 + h];
    wsf[WSF_X0 + h] = s;
  }
  for (int j = tid; j < 128; j += nth){
    float sd = drb0[j], sg = dib0[j];
    #pragma unroll
    for (int c = 0; c < 4; c++){
      sd += cond[c] * drW0[(65+c)*128 + j];
      sg += cond[c] * diW0[(65+c)*128 + j];
    }
    wsf[WSF_BCD + j] = sd; wsf[WSF_BCG + j] = sg;
  }
  for (int d = tid; d < 8; d += nth){
    float s = rob[d];
    #pragma unroll
    for (int c = 0; c < 4; c++) s += cond[c] * roW[(64+c)*8 + d];
    wsf[WSF_ROB + d] = s;
  }
  for (int u = tid; u < 49152; u += nth){
    int j = u & 7, lane = (u >> 3) & 63, frag = u >> 9;
    int k8 = ((lane >> 4) << 3) + j, o16 = lane & 15;
    float v;
    if (frag < 16)      { int kc = frag & 1,      ot = frag >> 1;      v = drW0[(1 + kc*32 + k8)*128 + ot*16 + o16]; }
    else if (frag < 48) { int f = frag - 16; int kc = f & 3, ot = f >> 2; v = 0.909f * drW1[(kc*32 + k8)*128 + ot*16 + o16]; }
    else if (frag < 64) { int f = frag - 48; int kc = f & 1, ot = f >> 1; v = diW0[(1 + kc*32 + k8)*128 + ot*16 + o16]; }
    else                { int f = frag - 64; int kc = f & 3, ot = f >> 2; v = 0.909f * diW1[(kc*32 + k8)*128 + ot*16 + o16]; }
    wsm[u] = f2bf(v);
  }
  for (int u = tid; u < 8192; u += nth){   // Wd2 [128x64], KC=4, ot 0..3
    int j = u & 7, lane = (u >> 3) & 63, frag = u >> 9, kc = frag & 3, ot = frag >> 2;
    wd2[u] = f2bf(0.909f * drW2[(kc*32 + ((lane>>4)<<3) + j)*64 + ot*16 + (lane & 15)]);
  }
  for (int u = tid; u < 131072; u += nth){ // Wg2 [128x1024], KC=4, ot 0..63
    int j = u & 7, lane = (u >> 3) & 63, frag = u >> 9, kc = frag & 3, ot = frag >> 2;
    wg2[u] = f2bf(0.909f * diW2[(kc*32 + ((lane>>4)<<3) + j)*1024 + ot*16 + (lane & 15)]);
  }
  for (int u = tid; u < 1024; u += nth){   // roW [64][16-pad], KC=2, 1 ot
    int j = u & 7, lane = (u >> 3) & 63, kc = u >> 9;
    int k = kc*32 + ((lane>>4)<<3) + j, o = lane & 15;
    rwp[u] = (o < 8) ? f2bf(roW[k*8 + o]) : (unsigned short)0;
  }
}

// ============================================================
// main persistent kernel: 256 blocks x 1024 threads (16 waves),
// 32 batch rows per block, whole time loop on-chip.
// DESIGNED FOR 64 VGPRs: no fragment array is register-cached across
// a phase; every weight/activation fragment is (re)loaded from LDS or
// L2 inside the innermost kc loop (live set ~32-45 regs). Rounds 3-5
// proved the allocator pins 1024-thread kernels at 64 VGPR and spills
// (2.3 GB/dispatch scratch) rather than relax, ignoring waves_per_eu.
// ============================================================
__global__ __launch_bounds__(THREADS) void sde_kernel(
    const float* __restrict__ dW,  const float* __restrict__ tsg,
    const float* __restrict__ drW0, const float* __restrict__ diW0, // row0 = t weights
    const float* __restrict__ bd1, const float* __restrict__ bg1,
    const float* __restrict__ bd2, const float* __restrict__ bg2,
    const char* __restrict__ ws, float* __restrict__ out)
{
  __shared__ unsigned short smallW[49152];  // 96 KB packed weights
  __shared__ unsigned short z1buf[2048];    // [32][64] bf16, swizzled
  __shared__ unsigned short ybuf[2048];     // [32][64] bf16, swizzled (y for readout)
  __shared__ unsigned short h1d[4096];      // [32][128] bf16 swz | doubles as bT f32[64][32]
  __shared__ unsigned short h1g[4096];      // [32][128] bf16 swz | doubles as aT f32[64][32]
  __shared__ unsigned short h2d[4096];
  __shared__ unsigned short h2g[4096];
  __shared__ float f1T[2048];               // [64][32] f32, idx = h*32 + (brow^(h&31))
  __shared__ float tsbuf[128];
  __shared__ float bcdS[128], bcgS[128];    // layer0 cond biases
  __shared__ float wtdS[128], wtgS[128];    // layer0 t-row weights
  __shared__ float bd1S[128], bg1S[128];    // layer1 biases
  __shared__ float bg2S[1024];              // diff layer2 bias
  __shared__ float dwcS[512], dwnS[512];    // dW[k][B0..B0+31][16], dW[k+1][...]
  __shared__ float robiasS[8];

  const float* wsf = (const float*)ws;
  const unsigned short* wsSmall = (const unsigned short*)(ws + WSB_SMALL);
  const unsigned short* wsWd2   = (const unsigned short*)(ws + WSB_WD2);
  const unsigned short* wsWg2   = (const unsigned short*)(ws + WSB_WG2);
  const unsigned short* wsRoWp  = (const unsigned short*)(ws + WSB_ROWP);

  const int tid = threadIdx.x;
  const int w  = tid >> 6;        // wave 0..15
  const int l  = tid & 63;        // lane
  const int lg = l >> 4;          // 0..3
  const int li = l & 15;          // 0..15
  const int B0 = blockIdx.x * ROWS;
  const int row = tid >> 5;           // 0..31  (elementwise mapping)
  const int h0  = (tid & 31) << 1;    // 0..62  (2 h-slots per thread)

  // ---- init staging ----
  {
    const uint4* src = (const uint4*)wsSmall;
    uint4* dst = (uint4*)smallW;
    for (int i = tid; i < 6144; i += THREADS) dst[i] = src[i];
    for (int i = tid; i < 128; i += THREADS){
      tsbuf[i] = tsg[i];
      bcdS[i] = wsf[WSF_BCD + i]; bcgS[i] = wsf[WSF_BCG + i];
      wtdS[i] = drW0[i];          wtgS[i] = diW0[i];
      bd1S[i] = bd1[i];           bg1S[i] = bg1[i];
    }
    for (int i = tid; i < 1024; i += THREADS) bg2S[i] = bg2[i];
    if (tid < 8) robiasS[tid] = wsf[WSF_ROB + tid];
  }

  // ---- per-thread state (2 h-slots each) ----
  float y[2], z[2], fz[2], az[2];
  #pragma unroll
  for (int j = 0; j < 2; j++){ float v = wsf[WSF_X0 + h0 + j]; y[j] = v; z[j] = v; }

  auto writeZ = [&](){
    unsigned v = cvtpk(z[0], z[1]);
    int off = row*128 + (h0 << 1); off ^= (row & 7) << 4;
    *(unsigned*)((char*)z1buf + off) = v;
  };
  auto writeY = [&](){
    unsigned v = cvtpk(y[0], y[1]);
    int off = row*128 + (h0 << 1); off ^= (row & 7) << 4;
    *(unsigned*)((char*)ybuf + off) = v;
  };
  writeZ(); writeY();   // z1buf <- x0, ybuf <- x0

  __syncthreads();

  // readout projection: waves 14/15, tile bm = w-14; done in P1 phase
  auto OUTPROJ = [&](int tcur){
    const int bm = w - 14, brow = bm*16 + li;
    f32x4 acc = {0.f,0.f,0.f,0.f};
    #pragma unroll
    for (int kc = 0; kc < 2; kc++){
      bf16x8 rw = *(const bf16x8*)(wsRoWp + ((kc*64 + l) << 3));
      bf16x8 yb = lds_bfrag(ybuf, 128, brow, kc*64 + lg*16);
      acc = mfma16(rw, yb, acc);
    }
    float* orow = out + (size_t)(B0 + brow)*1152 + (size_t)tcur*9;
    if (lg < 2){
      #pragma unroll
      for (int r = 0; r < 4; r++) orow[1 + lg*4 + r] = acc[r] + robiasS[lg*4 + r];
    } else if (lg == 2){
      orow[0] = tsbuf[tcur];
    }
  };

  // ---- one full MLP pipeline evaluation at (tval, z1buf) ----
  auto PIPE = [&](float tval, int kdwc, int kdwn, int tcur){
    // stage dW slices into LDS (2 KB each, contiguous)
    if (tid < 256){
      const float* src = dW + ((tid < 128) ? (size_t)kdwc : (size_t)kdwn)*131072
                            + (size_t)B0*16;
      float* dst = (tid < 128) ? dwcS : dwnS;
      int i = tid & 127;
      *(f32x4*)(dst + i*4) = *(const f32x4*)(src + i*4);
    }
    // ---- P1: layer0 drift+diff : [128 out]x[32], K=64; wave = (p, ot) ----
    {
      const int p = w >> 3, ot = w & 7;
      const int base = p ? 24576 : 0;
      unsigned short* hout = p ? h1g : h1d;
      f32x4 acc0 = {0.f,0.f,0.f,0.f}, acc1 = {0.f,0.f,0.f,0.f};
      #pragma unroll
      for (int kc = 0; kc < 2; kc++){
        bf16x8 af = *(const bf16x8*)(smallW + base + ((ot*2 + kc)*64 + l)*8);
        bf16x8 z0 = lds_bfrag(z1buf, 128,      li, kc*64 + lg*16);
        bf16x8 z1 = lds_bfrag(z1buf, 128, 16 + li, kc*64 + lg*16);
        acc0 = mfma16(af, z0, acc0);
        acc1 = mfma16(af, z1, acc1);
      }
      f32x4 bcv = *(const f32x4*)((p ? bcgS : bcdS) + ot*16 + lg*4);
      f32x4 wtv = *(const f32x4*)((p ? wtgS : wtdS) + ot*16 + lg*4);
      #pragma unroll
      for (int bm = 0; bm < 2; bm++){
        const f32x4& acc = bm ? acc1 : acc0;
        int brow = bm*16 + li;
        float xx[4];
        #pragma unroll
        for (int r = 0; r < 4; r++) xx[r] = swishf(acc[r] + bcv[r] + tval*wtv[r]);
        int off = brow*256 + ((ot*16 + lg*4) << 1); off ^= (brow & 7) << 4;
        uint2 v; v.x = cvtpk(xx[0], xx[1]); v.y = cvtpk(xx[2], xx[3]);
        *(uint2*)((char*)hout + off) = v;
      }
      if (tcur >= 0 && w >= 14) OUTPROJ(tcur);
    }
    __syncthreads();
    // ---- P2: layer1 : wave = (p, ot), K=128 ----
    {
      const int p = w >> 3, ot = w & 7;
      const unsigned short* hin  = p ? h1g : h1d;
      unsigned short*       hout = p ? h2g : h2d;
      const int base = p ? 32768 : 8192;
      f32x4 acc0 = {0.f,0.f,0.f,0.f}, acc1 = {0.f,0.f,0.f,0.f};
      #pragma unroll
      for (int kc = 0; kc < 4; kc++){
        bf16x8 af = *(const bf16x8*)(smallW + base + ((ot*4 + kc)*64 + l)*8);
        bf16x8 hb0 = lds_bfrag(hin, 256,      li, kc*64 + lg*16);
        bf16x8 hb1 = lds_bfrag(hin, 256, 16 + li, kc*64 + lg*16);
        acc0 = mfma16(af, hb0, acc0);
        acc1 = mfma16(af, hb1, acc1);
      }
      f32x4 b1v = *(const f32x4*)((p ? bg1S : bd1S) + ot*16 + lg*4);
      #pragma unroll
      for (int bm = 0; bm < 2; bm++){
        const f32x4& acc = bm ? acc1 : acc0;
        int brow = bm*16 + li;
        float xx[4];
        #pragma unroll
        for (int r = 0; r < 4; r++) xx[r] = swishf(acc[r] + b1v[r]);
        int off = brow*256 + ((ot*16 + lg*4) << 1); off ^= (brow & 7) << 4;
        uint2 v; v.x = cvtpk(xx[0], xx[1]); v.y = cvtpk(xx[2], xx[3]);
        *(uint2*)((char*)hout + off) = v;
      }
    }
    __syncthreads();
    // ---- P3: drift L2 (waves 0-7) + diff L2 (all waves, 4 h each) ----
    {
      float* bT = (float*)h1d;
      float* aT = (float*)h1g;
      if (w < 8){ // drift: subtile (ot=w>>1, bm=w&1); weights streamed from L2
        const int ot = w >> 1, bm = w & 1, brow = bm*16 + li;
        f32x4 acc = {0.f,0.f,0.f,0.f};
        #pragma unroll
        for (int kc = 0; kc < 4; kc++){
          bf16x8 wf = *(const bf16x8*)(wsWd2 + ((ot*4 + kc)*64 + l)*8);
          bf16x8 db = lds_bfrag(h2d, 256, brow, kc*64 + lg*16);
          acc = mfma16(wf, db, acc);
        }
        f32x4 bdv = *(const f32x4*)(bd2 + ot*16 + lg*4);
        #pragma unroll
        for (int r = 0; r < 4; r++){
          int h = ot*16 + lg*4 + r;
          f1T[h*32 + (brow ^ (h & 31))] = tanhfast(acc[r] + bdv[r]);
        }
      }
      // diffusion: wave handles h = w*4 .. w*4+3; Wg2 streamed from L2;
      // all fragments loaded inside the kc loop (live set ~44 regs)
      #pragma unroll 1
      for (int ot = 0; ot < 4; ot++){
        const int h = w*4 + ot;
        f32x4 acc0 = {0.f,0.f,0.f,0.f}, acc1 = {0.f,0.f,0.f,0.f};
        #pragma unroll
        for (int kc = 0; kc < 4; kc++){
          bf16x8 fk = *(const bf16x8*)(wsWg2 + (((h*4 + kc)*64 + l) << 3));
          bf16x8 g0 = lds_bfrag(h2g, 256,      li, kc*64 + lg*16);
          bf16x8 g1 = lds_bfrag(h2g, 256, 16 + li, kc*64 + lg*16);
          acc0 = mfma16(fk, g0, acc0);
          acc1 = mfma16(fk, g1, acc1);
        }
        f32x4 bgv = *(const f32x4*)(bg2S + h*16 + lg*4);
        #pragma unroll
        for (int bm = 0; bm < 2; bm++){
          const f32x4& acc = bm ? acc1 : acc0;
          const int brow = bm*16 + li;
          f32x4 dwcv = *(const f32x4*)(dwcS + brow*16 + lg*4);
          f32x4 dwnv = *(const f32x4*)(dwnS + brow*16 + lg*4);
          float bs = 0.f, as_ = 0.f;
          #pragma unroll
          for (int r = 0; r < 4; r++){
            float g = tanhfast(acc[r] + bgv[r]);
            bs  += g * dwcv[r];
            as_ += g * dwnv[r];
          }
          bs  += __shfl_xor(bs, 16);  bs  += __shfl_xor(bs, 32);
          as_ += __shfl_xor(as_, 16); as_ += __shfl_xor(as_, 32);
          const int idx = h*32 + (brow ^ (h & 31));
          if (lg == 0)      bT[idx] = bs;
          else if (lg == 1) aT[idx] = as_;
        }
      }
    }
  };

  // ---- prologue: f0, g0 at (t0, x0); out(0) deferred to loop iter 0 ----
  PIPE(tsbuf[0], 0, 0, -1);
  __syncthreads();
  {
    #pragma unroll
    for (int j = 0; j < 2; j++){
      int h = h0 + j; int idx = h*32 + (row ^ (h & 31));
      fz[j] = f1T[idx];
      az[j] = ((const float*)h1g)[idx];      // a0 = g0 @ dW[0]
    }
    float dt0 = tsbuf[1] - tsbuf[0];
    #pragma unroll
    for (int j = 0; j < 2; j++) z[j] = 2.f*y[j] - z[j] + fz[j]*dt0 + az[j];
    writeZ();
  }
  __syncthreads();

  // ---- main time loop: iter k computes step k+1 and projects out(t=k) ----
  for (int k = 0; k < 127; k++){
    PIPE(tsbuf[k+1], k, (k < 126) ? (k+1) : 126, k);
    __syncthreads();
    float f1[2], bb[2], an[2];
    #pragma unroll
    for (int j = 0; j < 2; j++){
      int h = h0 + j; int idx = h*32 + (row ^ (h & 31));
      f1[j] = f1T[idx];
      bb[j] = ((const float*)h1d)[idx];
      an[j] = ((const float*)h1g)[idx];
    }
    float dtk = tsbuf[k+1] - tsbuf[k];
    #pragma unroll
    for (int j = 0; j < 2; j++){
      y[j] += 0.5f*dtk*(fz[j] + f1[j]) + 0.5f*(az[j] + bb[j]);
      fz[j] = f1[j]; az[j] = an[j];
    }
    writeY();
    if (k < 126){
      float dtn = tsbuf[k+2] - tsbuf[k+1];
      #pragma unroll
      for (int j = 0; j < 2; j++) z[j] = 2.f*y[j] - z[j] + fz[j]*dtn + az[j];
      writeZ();
    }
    __syncthreads();
  }

  // ---- epilogue: project out(t=127) from final ybuf ----
  if (w >= 14) OUTPROJ(127);
}

// ============================================================
extern "C" void kernel_launch(void* const* d_in, const int* in_sizes, int n_in,
                              void* d_out, int out_size, void* d_ws, size_t ws_size,
                              hipStream_t stream)
{
  const float* ts   = (const float*)d_in[0];
  const float* cond = (const float*)d_in[1];
  const float* dW   = (const float*)d_in[2];
  const float* drW0 = (const float*)d_in[3];
  const float* drb0 = (const float*)d_in[4];
  const float* drW1 = (const float*)d_in[5];
  const float* drb1 = (const float*)d_in[6];
  const float* drW2 = (const float*)d_in[7];
  const float* drb2 = (const float*)d_in[8];
  const float* diW0 = (const float*)d_in[9];
  const float* dib0 = (const float*)d_in[10];
  const float* diW1 = (const float*)d_in[11];
  const float* dib1 = (const float*)d_in[12];
  const float* diW2 = (const float*)d_in[13];
  const float* dib2 = (const float*)d_in[14];
  const float* initW= (const float*)d_in[15];
  const float* initb= (const float*)d_in[16];
  const float* roW  = (const float*)d_in[17];
  const float* rob  = (const float*)d_in[18];
  char* ws = (char*)d_ws;
  if (ws_size < (size_t)WSB_TOTAL) return;

  prep_kernel<<<dim3(256), dim3(256), 0, stream>>>(
      cond, drW0, drb0, drW1, drW2, diW0, dib0, diW1, diW2,
      initW, initb, roW, rob, ws);
  sde_kernel<<<dim3(256), dim3(THREADS), 0, stream>>>(
      dW, ts, drW0, diW0, drb1, dib1, drb2, dib2, ws, (float*)d_out);
}